// Round 1
// baseline (1158.819 us; speedup 1.0000x reference)
//
#include <hip/hip_runtime.h>

// VQ-VAE quantize forward, MI355X fp32 baseline.
// out = [values (BT*D)] [indexes as float (BT)] [loss (1)]

#define BT     65536      // 16 * 4096 rows
#define D      256        // codeword size
#define KCB    1024       // codebook size
#define BM     64         // rows per block
#define BN     64         // cols per N-tile
#define BK     64         // K chunk
#define LDK    68         // BK + 4: float4-aligned LDS rows, bank spread 4m+k

__global__ __launch_bounds__(256) void enorm_kernel(const float* __restrict__ E,
                                                    float* __restrict__ enorm) {
    const int wave = threadIdx.x >> 6;
    const int lane = threadIdx.x & 63;
    const int k = blockIdx.x * 4 + wave;
    float4 v = *(const float4*)(E + (size_t)k * D + lane * 4);
    float s = v.x*v.x + v.y*v.y + v.z*v.z + v.w*v.w;
    #pragma unroll
    for (int off = 1; off < 64; off <<= 1) s += __shfl_xor(s, off, 64);
    if (lane == 0) enorm[k] = s;
}

__global__ __launch_bounds__(256) void vq_kernel(const float* __restrict__ X,
                                                 const float* __restrict__ E,
                                                 const float* __restrict__ enorm,
                                                 float* __restrict__ out_vals,
                                                 float* __restrict__ out_idx,
                                                 float* __restrict__ out_loss) {
    __shared__ float As[BM][LDK];
    __shared__ float Bs[BN][LDK];
    __shared__ float s_bd[BM];
    __shared__ int   s_bi[BM];
    __shared__ float s_red[4];

    const int tid  = threadIdx.x;
    const int tx   = tid & 15;       // col group
    const int ty   = tid >> 4;       // row group
    const int row0 = blockIdx.x * BM;

    if (tid < BM) { s_bd[tid] = 3.4e38f; s_bi[tid] = 0; }

    for (int nt = 0; nt < KCB / BN; ++nt) {
        const int col0 = nt * BN;
        float acc[4][4];
        #pragma unroll
        for (int i = 0; i < 4; ++i)
            #pragma unroll
            for (int j = 0; j < 4; ++j) acc[i][j] = 0.f;

        for (int kc = 0; kc < D; kc += BK) {
            __syncthreads();   // protect previous tile reads (and s_bd init on iter 0)
            // stage A (64 rows x 64 k) and B (64 cols x 64 k), row-major, coalesced f4
            #pragma unroll
            for (int u = 0; u < 4; ++u) {
                const int f  = tid + 256 * u;
                const int m  = f >> 4;
                const int kq = (f & 15) << 2;
                *(float4*)&As[m][kq] = *(const float4*)(X + (size_t)(row0 + m) * D + kc + kq);
                *(float4*)&Bs[m][kq] = *(const float4*)(E + (size_t)(col0 + m) * D + kc + kq);
            }
            __syncthreads();
            // FMA loop: strided micro-tile rows ty+16i, cols tx+16j
            #pragma unroll
            for (int k = 0; k < BK; k += 4) {
                float4 a[4], b[4];
                #pragma unroll
                for (int i = 0; i < 4; ++i) a[i] = *(const float4*)&As[ty + 16*i][k];
                #pragma unroll
                for (int j = 0; j < 4; ++j) b[j] = *(const float4*)&Bs[tx + 16*j][k];
                #pragma unroll
                for (int i = 0; i < 4; ++i)
                    #pragma unroll
                    for (int j = 0; j < 4; ++j)
                        acc[i][j] += a[i].x*b[j].x + a[i].y*b[j].y
                                   + a[i].z*b[j].z + a[i].w*b[j].w;
            }
        }

        // score = |e|^2 - 2 x.e  (|x|^2 constant per row, argmin-invariant)
        float en[4];
        #pragma unroll
        for (int j = 0; j < 4; ++j) en[j] = enorm[col0 + tx + 16*j];

        #pragma unroll
        for (int i = 0; i < 4; ++i) {
            float bd = 3.4e38f; int bi = KCB;
            #pragma unroll
            for (int j = 0; j < 4; ++j) {
                const int c = col0 + tx + 16*j;
                const float s = en[j] - 2.f * acc[i][j];
                if (s < bd || (s == bd && c < bi)) { bd = s; bi = c; }
            }
            // reduce over the 16 tx lanes (lane bits 0..3 within the wave)
            #pragma unroll
            for (int off = 1; off < 16; off <<= 1) {
                const float od = __shfl_xor(bd, off, 64);
                const int   oi = __shfl_xor(bi, off, 64);
                if (od < bd || (od == bd && oi < bi)) { bd = od; bi = oi; }
            }
            if (tx == 0) {
                const int r = ty + 16*i;   // unique owner thread per row
                if (bd < s_bd[r] || (bd == s_bd[r] && bi < s_bi[r])) {
                    s_bd[r] = bd; s_bi[r] = bi;
                }
            }
        }
    }

    __syncthreads();

    // epilogue: values gather, straight-through output (== values), loss partial
    float lsum = 0.f;
    for (int r = 0; r < BM; ++r) {
        const int row = row0 + r;
        const int bi  = s_bi[r];
        const float xv = X[(size_t)row * D + tid];
        const float ev = E[(size_t)bi * D + tid];
        out_vals[(size_t)row * D + tid] = ev;
        const float dd = xv - ev;
        lsum += dd * dd;
    }
    if (tid < BM) out_idx[row0 + tid] = (float)s_bi[tid];

    #pragma unroll
    for (int off = 1; off < 64; off <<= 1) lsum += __shfl_xor(lsum, off, 64);
    if ((tid & 63) == 0) s_red[tid >> 6] = lsum;
    __syncthreads();
    if (tid == 0) {
        const float total = s_red[0] + s_red[1] + s_red[2] + s_red[3];
        // loss = loss1 + 0.1*loss2 ; forward value = 1.1 * mean((x-v)^2)
        atomicAdd(out_loss, total * (1.1f / 16777216.f));
    }
}

extern "C" void kernel_launch(void* const* d_in, const int* in_sizes, int n_in,
                              void* d_out, int out_size, void* d_ws, size_t ws_size,
                              hipStream_t stream) {
    const float* X = (const float*)d_in[0];
    const float* E = (const float*)d_in[1];
    float* out      = (float*)d_out;
    float* out_vals = out;
    float* out_idx  = out + (size_t)BT * D;
    float* out_loss = out + (size_t)BT * D + BT;
    float* enorm    = (float*)d_ws;

    hipMemsetAsync(out_loss, 0, sizeof(float), stream);  // d_out is poisoned 0xAA
    enorm_kernel<<<KCB / 4, 256, 0, stream>>>(E, enorm);
    vq_kernel<<<BT / BM, 256, 0, stream>>>(X, E, enorm, out_vals, out_idx, out_loss);
}

// Round 2
// 355.968 us; speedup vs baseline: 3.2554x; 3.2554x over previous
//
#include <hip/hip_runtime.h>
#include <stdint.h>

// VQ-VAE quantize forward, MI355X. Split-f16 MFMA distance GEMM.
// out = [values (BT*D)] [indexes as float (BT)] [loss (1)]

#define BT   65536      // 16*4096 rows
#define D    256        // codeword size
#define KCB  1024       // codebook size
#define BM   128        // rows per block tile
#define BN   128        // cols per n-tile
#define NT   (KCB/BN)   // 8 col tiles
#define BK   64         // k chunk

typedef float    f32x4 __attribute__((ext_vector_type(4)));
typedef _Float16 f16x8 __attribute__((ext_vector_type(8)));

#define GLOAD_LDS16(g, l) \
  __builtin_amdgcn_global_load_lds((const __attribute__((address_space(1))) void*)(g), \
                                   (__attribute__((address_space(3))) void*)(l), 16, 0, 0)

// ---- split X into f16 hi/lo (hi+lo captures ~23 bits: x - (float)(f16)x is exact) ----
__global__ __launch_bounds__(256) void split_x_kernel(const float* __restrict__ X,
                                                      _Float16* __restrict__ Xh,
                                                      _Float16* __restrict__ Xl) {
    const size_t i0 = ((size_t)blockIdx.x * 256 + threadIdx.x) * 8;
    float4 v0 = *(const float4*)(X + i0);
    float4 v1 = *(const float4*)(X + i0 + 4);
    float v[8] = {v0.x, v0.y, v0.z, v0.w, v1.x, v1.y, v1.z, v1.w};
    f16x8 h, l;
    #pragma unroll
    for (int j = 0; j < 8; ++j) {
        _Float16 hh = (_Float16)v[j];
        h[j] = hh;
        l[j] = (_Float16)(v[j] - (float)hh);
    }
    *(f16x8*)(Xh + i0) = h;
    *(f16x8*)(Xl + i0) = l;
}

// ---- split E + fp32 |e|^2 ----
__global__ __launch_bounds__(256) void split_e_kernel(const float* __restrict__ E,
                                                      _Float16* __restrict__ Eh,
                                                      _Float16* __restrict__ El,
                                                      float* __restrict__ enorm) {
    const int wave = threadIdx.x >> 6;
    const int lane = threadIdx.x & 63;
    const int r = blockIdx.x * 4 + wave;
    const size_t base = (size_t)r * D + lane * 4;
    float4 v = *(const float4*)(E + base);
    float s = v.x*v.x + v.y*v.y + v.z*v.z + v.w*v.w;
    float vv[4] = {v.x, v.y, v.z, v.w};
    _Float16 h4[4], l4[4];
    #pragma unroll
    for (int j = 0; j < 4; ++j) {
        _Float16 hh = (_Float16)vv[j];
        h4[j] = hh;
        l4[j] = (_Float16)(vv[j] - (float)hh);
    }
    *(ushort4*)(Eh + base) = *(ushort4*)h4;
    *(ushort4*)(El + base) = *(ushort4*)l4;
    #pragma unroll
    for (int off = 1; off < 64; off <<= 1) s += __shfl_xor(s, off, 64);
    if (lane == 0) enorm[r] = s;
}

// ---- main: distance GEMM (3-pass split-f16 MFMA) + argmin + gather + loss ----
__global__ __launch_bounds__(256) void vq_mfma_kernel(
    const float* __restrict__ X, const float* __restrict__ E,
    const _Float16* __restrict__ Xh, const _Float16* __restrict__ Xl,
    const _Float16* __restrict__ Eh, const _Float16* __restrict__ El,
    const float* __restrict__ enorm,
    float* __restrict__ out_vals, float* __restrict__ out_idx,
    float* __restrict__ out_loss) {
    __shared__ __align__(16) _Float16 As[BM * BK];   // 16 KB, row-major [m][k]
    __shared__ __align__(16) _Float16 Bs[BN * BK];   // 16 KB, row-major [n][k] (B^T)
    __shared__ float s_bd[BM];
    __shared__ int   s_bi[BM];
    __shared__ float s_red[4];

    const int tid  = threadIdx.x;
    const int w    = tid >> 6;
    const int lane = tid & 63;
    const int wm   = w >> 1;          // wave row (0..1)
    const int wn   = w & 1;           // wave col (0..1)
    const int quad = lane >> 4;
    const int l16  = lane & 15;
    const int row0 = blockIdx.x * BM;

    // staging geometry: 16 chunks of 1KB; wave w owns chunks w*4..w*4+3
    // chunk c covers tile rows c*8..c*8+7; lane: row c*8+(lane>>3), 8 f16 at (lane&7)*8
    const int s_row  = lane >> 3;
    const int s_col8 = (lane & 7) * 8;

    float rb_d[4][4];
    int   rb_i[4][4];
    #pragma unroll
    for (int i = 0; i < 4; ++i)
        #pragma unroll
        for (int r = 0; r < 4; ++r) { rb_d[i][r] = 3.4e38f; rb_i[i][r] = 0; }

    for (int nt = 0; nt < NT; ++nt) {
        const int col0 = nt * BN;
        f32x4 acc[4][4];
        #pragma unroll
        for (int i = 0; i < 4; ++i)
            #pragma unroll
            for (int j = 0; j < 4; ++j) acc[i][j] = (f32x4)0.0f;

        #pragma unroll
        for (int p = 0; p < 3; ++p) {
            const _Float16* Ap = (p == 1) ? Xl : Xh;
            const _Float16* Bp = (p == 2) ? El : Eh;
            for (int kc = 0; kc < D; kc += BK) {
                __syncthreads();      // previous tile fully consumed
                #pragma unroll
                for (int t = 0; t < 4; ++t) {
                    const int chunk = w * 4 + t;
                    const int r = chunk * 8 + s_row;
                    GLOAD_LDS16(Ap + (size_t)(row0 + r) * D + kc + s_col8, &As[chunk * 512]);
                    GLOAD_LDS16(Bp + (size_t)(col0 + r) * D + kc + s_col8, &Bs[chunk * 512]);
                }
                __syncthreads();      // waits vmcnt(0): staging landed
                #pragma unroll
                for (int ks = 0; ks < 2; ++ks) {
                    f16x8 a[4], b[4];
                    #pragma unroll
                    for (int i = 0; i < 4; ++i)
                        a[i] = *(const f16x8*)&As[(wm * 64 + i * 16 + l16) * BK + ks * 32 + quad * 8];
                    #pragma unroll
                    for (int j = 0; j < 4; ++j)
                        b[j] = *(const f16x8*)&Bs[(wn * 64 + j * 16 + l16) * BK + ks * 32 + quad * 8];
                    #pragma unroll
                    for (int i = 0; i < 4; ++i)
                        #pragma unroll
                        for (int j = 0; j < 4; ++j)
                            acc[i][j] = __builtin_amdgcn_mfma_f32_16x16x32_f16(a[i], b[j], acc[i][j], 0, 0, 0);
                }
            }
        }

        // score = |e|^2 - 2 x.e ; running per-lane argmin (cols ascend -> strict <)
        #pragma unroll
        for (int j = 0; j < 4; ++j) {
            const int c = col0 + wn * 64 + j * 16 + l16;
            const float en = enorm[c];
            #pragma unroll
            for (int i = 0; i < 4; ++i)
                #pragma unroll
                for (int r = 0; r < 4; ++r) {
                    const float s = en - 2.0f * acc[i][j][r];
                    if (s < rb_d[i][r]) { rb_d[i][r] = s; rb_i[i][r] = c; }
                }
        }
    }

    // fold the 16 lanes of each quad (they partition the wave's 64-col slices)
    #pragma unroll
    for (int off = 1; off < 16; off <<= 1) {
        #pragma unroll
        for (int i = 0; i < 4; ++i)
            #pragma unroll
            for (int r = 0; r < 4; ++r) {
                const float od = __shfl_xor(rb_d[i][r], off, 64);
                const int   oi = __shfl_xor(rb_i[i][r], off, 64);
                if (od < rb_d[i][r] || (od == rb_d[i][r] && oi < rb_i[i][r])) {
                    rb_d[i][r] = od; rb_i[i][r] = oi;
                }
            }
    }
    // two-phase deterministic merge of the wn=0 / wn=1 halves
    if (wn == 0 && l16 == 0) {
        #pragma unroll
        for (int i = 0; i < 4; ++i)
            #pragma unroll
            for (int r = 0; r < 4; ++r) {
                const int m = wm * 64 + i * 16 + quad * 4 + r;
                s_bd[m] = rb_d[i][r]; s_bi[m] = rb_i[i][r];
            }
    }
    __syncthreads();
    if (wn == 1 && l16 == 0) {
        #pragma unroll
        for (int i = 0; i < 4; ++i)
            #pragma unroll
            for (int r = 0; r < 4; ++r) {
                const int m = wm * 64 + i * 16 + quad * 4 + r;
                if (rb_d[i][r] < s_bd[m] || (rb_d[i][r] == s_bd[m] && rb_i[i][r] < s_bi[m])) {
                    s_bd[m] = rb_d[i][r]; s_bi[m] = rb_i[i][r];
                }
            }
    }
    __syncthreads();

    // epilogue: gather values (straight-through fwd == values), loss partial
    float lsum = 0.f;
    for (int r = 0; r < BM; ++r) {
        const int row = row0 + r;
        const int bi  = s_bi[r];
        const float xv = X[(size_t)row * D + tid];
        const float ev = E[(size_t)bi * D + tid];
        out_vals[(size_t)row * D + tid] = ev;
        const float dd = xv - ev;
        lsum += dd * dd;
    }
    if (tid < BM) out_idx[row0 + tid] = (float)s_bi[tid];

    #pragma unroll
    for (int off = 1; off < 64; off <<= 1) lsum += __shfl_xor(lsum, off, 64);
    if (lane == 0) s_red[w] = lsum;
    __syncthreads();
    if (tid == 0) {
        const float total = s_red[0] + s_red[1] + s_red[2] + s_red[3];
        atomicAdd(out_loss, total * (1.1f / 16777216.f));  // loss1 + 0.1*loss2
    }
}

extern "C" void kernel_launch(void* const* d_in, const int* in_sizes, int n_in,
                              void* d_out, int out_size, void* d_ws, size_t ws_size,
                              hipStream_t stream) {
    const float* X = (const float*)d_in[0];
    const float* E = (const float*)d_in[1];
    float* out      = (float*)d_out;
    float* out_vals = out;
    float* out_idx  = out + (size_t)BT * D;
    float* out_loss = out + (size_t)BT * D + BT;

    char* ws = (char*)d_ws;
    _Float16* Xh = (_Float16*)ws;
    _Float16* Xl = Xh + (size_t)BT * D;
    _Float16* Eh = Xl + (size_t)BT * D;
    _Float16* El = Eh + (size_t)KCB * D;
    float*    enorm = (float*)(El + (size_t)KCB * D);
    (void)ws_size; (void)n_in; (void)in_sizes; (void)out_size;

    hipMemsetAsync(out_loss, 0, sizeof(float), stream);  // d_out poisoned 0xAA
    split_x_kernel<<<(BT * D) / 2048, 256, 0, stream>>>(X, Xh, Xl);
    split_e_kernel<<<KCB / 4, 256, 0, stream>>>(E, Eh, El, enorm);
    vq_mfma_kernel<<<BT / BM, 256, 0, stream>>>(X, E, Xh, Xl, Eh, El, enorm,
                                                out_vals, out_idx, out_loss);
}

// Round 3
// 247.637 us; speedup vs baseline: 4.6795x; 1.4375x over previous
//
#include <hip/hip_runtime.h>
#include <stdint.h>

// VQ-VAE quantize forward, MI355X. Split-f16 MFMA distance GEMM.
// R3: XOR bank swizzle + fused 3-pass staging (16 ds_reads feed 48 MFMAs).
// out = [values (BT*D)] [indexes as float (BT)] [loss (1)]

#define BT   65536      // 16*4096 rows
#define D    256        // codeword size
#define KCB  1024       // codebook size
#define BM   128        // rows per block tile
#define BN   128        // cols per n-tile
#define NT   (KCB/BN)   // 8 col tiles
#define BK   64         // k chunk

typedef float    f32x4 __attribute__((ext_vector_type(4)));
typedef _Float16 f16x8 __attribute__((ext_vector_type(8)));

#define GLOAD_LDS16(g, l) \
  __builtin_amdgcn_global_load_lds((const __attribute__((address_space(1))) void*)(g), \
                                   (__attribute__((address_space(3))) void*)(l), 16, 0, 0)

// ---- split X into f16 hi/lo (x - (float)(f16)x is exact in f16) ----
__global__ __launch_bounds__(256) void split_x_kernel(const float* __restrict__ X,
                                                      _Float16* __restrict__ Xh,
                                                      _Float16* __restrict__ Xl) {
    const size_t i0 = ((size_t)blockIdx.x * 256 + threadIdx.x) * 8;
    float4 v0 = *(const float4*)(X + i0);
    float4 v1 = *(const float4*)(X + i0 + 4);
    float v[8] = {v0.x, v0.y, v0.z, v0.w, v1.x, v1.y, v1.z, v1.w};
    f16x8 h, l;
    #pragma unroll
    for (int j = 0; j < 8; ++j) {
        _Float16 hh = (_Float16)v[j];
        h[j] = hh;
        l[j] = (_Float16)(v[j] - (float)hh);
    }
    *(f16x8*)(Xh + i0) = h;
    *(f16x8*)(Xl + i0) = l;
}

// ---- split E + fp32 |e|^2 ----
__global__ __launch_bounds__(256) void split_e_kernel(const float* __restrict__ E,
                                                      _Float16* __restrict__ Eh,
                                                      _Float16* __restrict__ El,
                                                      float* __restrict__ enorm) {
    const int wave = threadIdx.x >> 6;
    const int lane = threadIdx.x & 63;
    const int r = blockIdx.x * 4 + wave;
    const size_t base = (size_t)r * D + lane * 4;
    float4 v = *(const float4*)(E + base);
    float s = v.x*v.x + v.y*v.y + v.z*v.z + v.w*v.w;
    float vv[4] = {v.x, v.y, v.z, v.w};
    _Float16 h4[4], l4[4];
    #pragma unroll
    for (int j = 0; j < 4; ++j) {
        _Float16 hh = (_Float16)vv[j];
        h4[j] = hh;
        l4[j] = (_Float16)(vv[j] - (float)hh);
    }
    *(ushort4*)(Eh + base) = *(ushort4*)h4;
    *(ushort4*)(El + base) = *(ushort4*)l4;
    #pragma unroll
    for (int off = 1; off < 64; off <<= 1) s += __shfl_xor(s, off, 64);
    if (lane == 0) enorm[r] = s;
}

// ---- main: fused 3-term split-f16 MFMA distance GEMM + argmin + gather + loss ----
__global__ __launch_bounds__(256, 2) void vq_mfma_kernel(
    const float* __restrict__ X, const float* __restrict__ E,
    const _Float16* __restrict__ Xh, const _Float16* __restrict__ Xl,
    const _Float16* __restrict__ Eh, const _Float16* __restrict__ El,
    const float* __restrict__ enorm,
    float* __restrict__ out_vals, float* __restrict__ out_idx,
    float* __restrict__ out_loss) {
    // 4 tiles of 128 rows x 64 k f16, 16 KB each. Physical layout is chunk-linear
    // (global_load_lds constraint); 16B col-chunk c of row r holds LOGICAL chunk
    // c ^ (r&7)  -> every 16-lane ds_read phase spreads over all 32 banks (2-way, free).
    __shared__ __align__(16) _Float16 Ash[BM * BK];
    __shared__ __align__(16) _Float16 Asl[BM * BK];
    __shared__ __align__(16) _Float16 Bsh[BN * BK];
    __shared__ __align__(16) _Float16 Bsl[BN * BK];
    __shared__ float s_bd[BM];
    __shared__ int   s_bi[BM];
    __shared__ float s_red[4];

    const int tid  = threadIdx.x;
    const int w    = tid >> 6;
    const int lane = tid & 63;
    const int wm   = w >> 1;          // wave row (0..1)
    const int wn   = w & 1;           // wave col (0..1)
    const int quad = lane >> 4;
    const int l16  = lane & 15;
    const int l8   = l16 & 7;
    const int row0 = blockIdx.x * BM;

    // staging: 16 chunks of 1KB per tile; wave w owns chunks w*4..w*4+3.
    // chunk covers 8 rows; lane -> row chunk*8+(lane>>3), fetches swizzled col chunk.
    const int s_row = lane >> 3;
    const int c_g   = (lane & 7) ^ s_row;     // XOR-swizzled global 16B col chunk
    const int s_off = c_g * 8;                // f16 offset within the 64-k row

    float rb_d[4][4];
    int   rb_i[4][4];
    #pragma unroll
    for (int i = 0; i < 4; ++i)
        #pragma unroll
        for (int r = 0; r < 4; ++r) { rb_d[i][r] = 3.4e38f; rb_i[i][r] = 0; }

    for (int nt = 0; nt < NT; ++nt) {
        const int col0 = nt * BN;
        f32x4 acc[4][4];
        #pragma unroll
        for (int i = 0; i < 4; ++i)
            #pragma unroll
            for (int j = 0; j < 4; ++j) acc[i][j] = (f32x4)0.0f;

        for (int kc = 0; kc < D; kc += BK) {
            __syncthreads();      // previous tile fully consumed
            #pragma unroll
            for (int t = 0; t < 4; ++t) {
                const int chunk = w * 4 + t;
                const int r = chunk * 8 + s_row;
                const size_t ga = (size_t)(row0 + r) * D + kc + s_off;
                const size_t gb = (size_t)(col0 + r) * D + kc + s_off;
                GLOAD_LDS16(Xh + ga, &Ash[chunk * 512]);
                GLOAD_LDS16(Xl + ga, &Asl[chunk * 512]);
                GLOAD_LDS16(Eh + gb, &Bsh[chunk * 512]);
                GLOAD_LDS16(El + gb, &Bsl[chunk * 512]);
            }
            __syncthreads();      // waits vmcnt(0): staging landed
            #pragma unroll
            for (int ks = 0; ks < 2; ++ks) {
                const int cl = ks * 4 + quad;              // logical 16B chunk in row
                const int ko = (cl ^ l8) * 8;              // physical f16 offset
                f16x8 ah[4], al[4], bh[4], bl[4];
                #pragma unroll
                for (int i = 0; i < 4; ++i) {
                    const int m = (wm * 64 + i * 16 + l16) * BK;
                    ah[i] = *(const f16x8*)&Ash[m + ko];
                    al[i] = *(const f16x8*)&Asl[m + ko];
                }
                #pragma unroll
                for (int j = 0; j < 4; ++j) {
                    const int n = (wn * 64 + j * 16 + l16) * BK;
                    bh[j] = *(const f16x8*)&Bsh[n + ko];
                    bl[j] = *(const f16x8*)&Bsl[n + ko];
                }
                #pragma unroll
                for (int i = 0; i < 4; ++i)
                    #pragma unroll
                    for (int j = 0; j < 4; ++j) {
                        acc[i][j] = __builtin_amdgcn_mfma_f32_16x16x32_f16(ah[i], bh[j], acc[i][j], 0, 0, 0);
                        acc[i][j] = __builtin_amdgcn_mfma_f32_16x16x32_f16(al[i], bh[j], acc[i][j], 0, 0, 0);
                        acc[i][j] = __builtin_amdgcn_mfma_f32_16x16x32_f16(ah[i], bl[j], acc[i][j], 0, 0, 0);
                    }
            }
        }

        // score = |e|^2 - 2 x.e ; running per-lane argmin (cols ascend -> strict <)
        #pragma unroll
        for (int j = 0; j < 4; ++j) {
            const int c = col0 + wn * 64 + j * 16 + l16;
            const float en = enorm[c];
            #pragma unroll
            for (int i = 0; i < 4; ++i)
                #pragma unroll
                for (int r = 0; r < 4; ++r) {
                    const float s = en - 2.0f * acc[i][j][r];
                    if (s < rb_d[i][r]) { rb_d[i][r] = s; rb_i[i][r] = c; }
                }
        }
    }

    // fold the 16 lanes of each quad (they partition the wave's col slices)
    #pragma unroll
    for (int off = 1; off < 16; off <<= 1) {
        #pragma unroll
        for (int i = 0; i < 4; ++i)
            #pragma unroll
            for (int r = 0; r < 4; ++r) {
                const float od = __shfl_xor(rb_d[i][r], off, 64);
                const int   oi = __shfl_xor(rb_i[i][r], off, 64);
                if (od < rb_d[i][r] || (od == rb_d[i][r] && oi < rb_i[i][r])) {
                    rb_d[i][r] = od; rb_i[i][r] = oi;
                }
            }
    }
    // two-phase deterministic merge of the wn=0 / wn=1 halves
    if (wn == 0 && l16 == 0) {
        #pragma unroll
        for (int i = 0; i < 4; ++i)
            #pragma unroll
            for (int r = 0; r < 4; ++r) {
                const int m = wm * 64 + i * 16 + quad * 4 + r;
                s_bd[m] = rb_d[i][r]; s_bi[m] = rb_i[i][r];
            }
    }
    __syncthreads();
    if (wn == 1 && l16 == 0) {
        #pragma unroll
        for (int i = 0; i < 4; ++i)
            #pragma unroll
            for (int r = 0; r < 4; ++r) {
                const int m = wm * 64 + i * 16 + quad * 4 + r;
                if (rb_d[i][r] < s_bd[m] || (rb_d[i][r] == s_bd[m] && rb_i[i][r] < s_bi[m])) {
                    s_bd[m] = rb_d[i][r]; s_bi[m] = rb_i[i][r];
                }
            }
    }
    __syncthreads();

    // epilogue: gather values (straight-through fwd == values), loss partial
    float lsum = 0.f;
    for (int r = 0; r < BM; ++r) {
        const int row = row0 + r;
        const int bi  = s_bi[r];
        const float xv = X[(size_t)row * D + tid];
        const float ev = E[(size_t)bi * D + tid];
        out_vals[(size_t)row * D + tid] = ev;
        const float dd = xv - ev;
        lsum += dd * dd;
    }
    if (tid < BM) out_idx[row0 + tid] = (float)s_bi[tid];

    #pragma unroll
    for (int off = 1; off < 64; off <<= 1) lsum += __shfl_xor(lsum, off, 64);
    if (lane == 0) s_red[w] = lsum;
    __syncthreads();
    if (tid == 0) {
        const float total = s_red[0] + s_red[1] + s_red[2] + s_red[3];
        atomicAdd(out_loss, total * (1.1f / 16777216.f));  // loss1 + 0.1*loss2
    }
}

extern "C" void kernel_launch(void* const* d_in, const int* in_sizes, int n_in,
                              void* d_out, int out_size, void* d_ws, size_t ws_size,
                              hipStream_t stream) {
    const float* X = (const float*)d_in[0];
    const float* E = (const float*)d_in[1];
    float* out      = (float*)d_out;
    float* out_vals = out;
    float* out_idx  = out + (size_t)BT * D;
    float* out_loss = out + (size_t)BT * D + BT;

    char* ws = (char*)d_ws;
    _Float16* Xh = (_Float16*)ws;
    _Float16* Xl = Xh + (size_t)BT * D;
    _Float16* Eh = Xl + (size_t)BT * D;
    _Float16* El = Eh + (size_t)KCB * D;
    float*    enorm = (float*)(El + (size_t)KCB * D);
    (void)ws_size; (void)n_in; (void)in_sizes; (void)out_size;

    hipMemsetAsync(out_loss, 0, sizeof(float), stream);  // d_out poisoned 0xAA
    split_x_kernel<<<(BT * D) / 2048, 256, 0, stream>>>(X, Xh, Xl);
    split_e_kernel<<<KCB / 4, 256, 0, stream>>>(E, Eh, El, enorm);
    vq_mfma_kernel<<<BT / BM, 256, 0, stream>>>(X, E, Xh, Xl, Eh, El, enorm,
                                                out_vals, out_idx, out_loss);
}